// Round 20
// baseline (133.892 us; speedup 1.0000x reference)
//
#include <hip/hip_runtime.h>
#include <hip/hip_bf16.h>

typedef __attribute__((ext_vector_type(8))) __bf16 bf16x8;
typedef __attribute__((ext_vector_type(4))) __bf16 bf16x4;
typedef __attribute__((ext_vector_type(4))) float f32x4;

#define MFMA16(a, b, c) __builtin_amdgcn_mfma_f32_16x16x32_bf16((a), (b), (c), 0, 0, 0)

static constexpr int DM = 1024;
static constexpr int SEQ = 2048;
static constexpr int NB = 2;
static constexpr int NH = 16;
static constexpr int DKK = 64;
static constexpr int MROWS = NB * SEQ;  // 4096

__device__ __forceinline__ void gload16(__bf16* lds, const __bf16* g) {
  __builtin_amdgcn_global_load_lds(
      (const __attribute__((address_space(1))) void*)g,
      (__attribute__((address_space(3))) void*)lds, 16, 0, 0);
}

// ---------------- fp32 -> bf16 weight pre-convert (4 weights only) ----------
__global__ __launch_bounds__(256) void cvt_w_kernel(
    const float* __restrict__ wq, const float* __restrict__ wk,
    const float* __restrict__ wv, const float* __restrict__ wo,
    __bf16* __restrict__ owq, __bf16* __restrict__ owk,
    __bf16* __restrict__ owv, __bf16* __restrict__ owo) {
  const unsigned id = blockIdx.x * 256 + threadIdx.x;  // 524,288 threads
  const int sel = id >> 17;
  const float* src = sel == 0 ? wq : sel == 1 ? wk : sel == 2 ? wv : wo;
  __bf16* dst = sel == 0 ? owq : sel == 1 ? owk : sel == 2 ? owv : owo;
  const size_t off = (size_t)(id & ((1u << 17) - 1)) * 8;
  f32x4 a = *(const f32x4*)(src + off);
  f32x4 b2 = *(const f32x4*)(src + off + 4);
  bf16x8 o;
#pragma unroll
  for (int j = 0; j < 4; ++j) { o[j] = (__bf16)a[j]; o[j + 4] = (__bf16)b2[j]; }
  *(bf16x8*)(dst + off) = o;
}

// ---------------- all-bf16 GEMM core (global_load_lds, dbuf, 1 barrier/K) ---
__device__ __forceinline__ void gemm_bt_core(
    const __bf16* __restrict__ X, const __bf16* __restrict__ W, int bm, int bn,
    f32x4 (&acc)[4][4], __bf16 (*As)[128][32], __bf16 (*Bs)[128][32]) {
  const int tid = threadIdx.x;
  const int lane = tid & 63;
  const int w = tid >> 6;
  const int g = lane >> 4, c = lane & 15;
  const int wm = (w >> 1) * 64, wn = (w & 1) * 64;
  const int lrow = lane >> 2;          // 0..15
  const int lseg = (lane & 3) * 8;     // 0,8,16,24
  auto stage = [&](int b, int k0) {
#pragma unroll
    for (int j = 0; j < 2; ++j) {
      const int r0 = w * 32 + j * 16;  // wave-uniform LDS base; HW adds lane*16
      gload16(&As[b][r0][0], X + (size_t)(bm + r0 + lrow) * DM + k0 + lseg);
      gload16(&Bs[b][r0][0], W + (size_t)(bn + r0 + lrow) * DM + k0 + lseg);
    }
  };
  stage(0, 0);
  __syncthreads();  // vmcnt(0) drain + barrier: tile 0 ready
  for (int ks = 0; ks < DM / 32; ++ks) {
    if (ks + 1 < DM / 32) stage((ks + 1) & 1, (ks + 1) * 32);  // in flight
    const int b = ks & 1;
    bf16x8 af[4], bfr[4];
#pragma unroll
    for (int i = 0; i < 4; ++i) {
      af[i] = *(const bf16x8*)&As[b][wm + i * 16 + c][g * 8];
      bfr[i] = *(const bf16x8*)&Bs[b][wn + i * 16 + c][g * 8];
    }
#pragma unroll
    for (int mi = 0; mi < 4; ++mi)
#pragma unroll
      for (int ni = 0; ni < 4; ++ni)
        acc[mi][ni] = MFMA16(af[mi], bfr[ni], acc[mi][ni]);
    __syncthreads();  // drains next tile's loads; one barrier per K-step
  }
}

// ---------------- Fused Q/K/V projection (fp32 X, 2-deep A prefetch) --------
__global__ __launch_bounds__(256, 2) void proj3_kernel(
    const float* __restrict__ Xq, const float* __restrict__ Xk,
    const float* __restrict__ Xv, const __bf16* __restrict__ Wq,
    const __bf16* __restrict__ Wk, const __bf16* __restrict__ Wv,
    __bf16* __restrict__ Yq, __bf16* __restrict__ Yk, __bf16* __restrict__ Yv) {
  __shared__ __bf16 As[2][128][32];
  __shared__ __bf16 Bs[2][128][32];
  const int bid = blockIdx.x;          // 0..767
  const int swz = (bid & 7) * 96 + (bid >> 3);  // bijective: 768 = 8*96
  const int z = swz >> 8;              // 0..2
  const int rem = swz & 255;
  const int bm = (rem >> 3) * 128;
  const int bn = (rem & 7) * 128;
  const float* X = (z == 0) ? Xq : (z == 1) ? Xk : Xv;
  const __bf16* W = (z == 0) ? Wq : (z == 1) ? Wk : Wv;
  __bf16* Y = (z == 0) ? Yq : (z == 1) ? Yk : Yv;
  const int tid = threadIdx.x;
  const int lane = tid & 63;
  const int w = tid >> 6;
  const int g = lane >> 4, c = lane & 15;
  const int wm = (w >> 1) * 64, wn = (w & 1) * 64;
  const int srow = tid >> 1;           // 0..127 (A-staging row)
  const int shalf = (tid & 1) * 16;    // 0 or 16
  const int lrow = lane >> 2;          // 0..15  (B-staging)
  const int lseg = (lane & 3) * 8;
  const float* ap0 = X + (size_t)(bm + srow) * DM + shalf;
  f32x4 raA[4], raB[4];
  auto ldTo = [&](f32x4 (&ra)[4], int k0) {
#pragma unroll
    for (int i = 0; i < 4; ++i) ra[i] = *(const f32x4*)(ap0 + k0 + i * 4);
  };
  auto stFrom = [&](int b, const f32x4 (&ra)[4]) {
    bf16x8 h0, h1;
#pragma unroll
    for (int j = 0; j < 8; ++j) {
      h0[j] = (__bf16)ra[j >> 2][j & 3];
      h1[j] = (__bf16)ra[2 + (j >> 2)][j & 3];
    }
    *(bf16x8*)&As[b][srow][shalf] = h0;
    *(bf16x8*)&As[b][srow][shalf + 8] = h1;
  };
  auto stB = [&](int b, int k0) {
#pragma unroll
    for (int j = 0; j < 2; ++j) {
      const int r0 = w * 32 + j * 16;  // wave-uniform base; HW adds lane*16
      gload16(&Bs[b][r0][0], W + (size_t)(bn + r0 + lrow) * DM + k0 + lseg);
    }
  };
  f32x4 acc[4][4] = {};
  ldTo(raB, 0);
  stB(0, 0);
  stFrom(0, raB);
  ldTo(raA, 32);
  __syncthreads();  // drains gload (vmcnt) + ds_write (lgkm): tile 0 ready
  for (int kk = 0; kk < 16; ++kk) {
    {  // even step: ks = 2kk, LDS buf0; raA holds tile ks+1
      const int ks = kk * 2;
      if (ks + 2 < 32) ldTo(raB, (ks + 2) * 32);
      if (ks + 1 < 32) stB(1, (ks + 1) * 32);
      bf16x8 af[4], bfr[4];
#pragma unroll
      for (int i = 0; i < 4; ++i) {
        af[i] = *(const bf16x8*)&As[0][wm + i * 16 + c][g * 8];
        bfr[i] = *(const bf16x8*)&Bs[0][wn + i * 16 + c][g * 8];
      }
#pragma unroll
      for (int mi = 0; mi < 4; ++mi)
#pragma unroll
        for (int ni = 0; ni < 4; ++ni)
          acc[mi][ni] = MFMA16(af[mi], bfr[ni], acc[mi][ni]);
      if (ks + 1 < 32) stFrom(1, raA);
      __syncthreads();
    }
    {  // odd step: ks = 2kk+1, LDS buf1; raB holds tile ks+1
      const int ks = kk * 2 + 1;
      if (ks + 2 < 32) ldTo(raA, (ks + 2) * 32);
      if (ks + 1 < 32) stB(0, (ks + 1) * 32);
      bf16x8 af[4], bfr[4];
#pragma unroll
      for (int i = 0; i < 4; ++i) {
        af[i] = *(const bf16x8*)&As[1][wm + i * 16 + c][g * 8];
        bfr[i] = *(const bf16x8*)&Bs[1][wn + i * 16 + c][g * 8];
      }
#pragma unroll
      for (int mi = 0; mi < 4; ++mi)
#pragma unroll
        for (int ni = 0; ni < 4; ++ni)
          acc[mi][ni] = MFMA16(af[mi], bfr[ni], acc[mi][ni]);
      if (ks + 1 < 32) stFrom(0, raB);
      __syncthreads();
    }
  }
  if (z == 2) {
    // V: transposed-tile layout [bh][s>>6][dk][s&63]; r-contiguous b64 stores
#pragma unroll
    for (int mi = 0; mi < 4; ++mi)
#pragma unroll
      for (int ni = 0; ni < 4; ++ni) {
        const int row = bm + wm + mi * 16 + g * 4;  // +r
        const int col = bn + wn + ni * 16 + c;
        const int b = row >> 11;
        const int s = row & (SEQ - 1);
        const int h = col >> 6;
        const int dk = col & 63;
        bf16x4 st;
#pragma unroll
        for (int r = 0; r < 4; ++r) st[r] = (__bf16)acc[mi][ni][r];
        *(bf16x4*)&Y[((size_t)((b * NH + h) * 32 + (s >> 6)) << 12) +
                     dk * 64 + (s & 63)] = st;
      }
  } else {
    // Q gets softmax scale folded in: 1/sqrt(64) * log2(e)
    const float qs = (z == 0) ? 0.1803368801f : 1.0f;
#pragma unroll
    for (int mi = 0; mi < 4; ++mi)
#pragma unroll
      for (int ni = 0; ni < 4; ++ni)
#pragma unroll
        for (int r = 0; r < 4; ++r) {
          const int row = bm + wm + mi * 16 + g * 4 + r;
          const int col = bn + wn + ni * 16 + c;
          const int b = row >> 11;
          const int s = row & (SEQ - 1);
          const int h = col >> 6;
          const int dk = col & 63;
          Y[((size_t)((b * NH + h) * SEQ + s) << 6) + dk] =
              (__bf16)(acc[mi][ni][r] * qs);
        }
  }
}

// ---------------- Output GEMM (XCD-chunked swizzle) ----------------
__global__ __launch_bounds__(256) void out_gemm_kernel(
    const __bf16* __restrict__ X, const __bf16* __restrict__ W,
    float* __restrict__ Y) {
  __shared__ __bf16 As[2][128][32];
  __shared__ __bf16 Bs[2][128][32];
  const int bid = blockIdx.x;          // 0..255
  const int swz = (bid & 7) * 32 + (bid >> 3);  // bijective: 256 = 8*32
  const int bm = (swz >> 3) * 128;
  const int bn = (swz & 7) * 128;
  f32x4 acc[4][4] = {};
  gemm_bt_core(X, W, bm, bn, acc, As, Bs);
  const int lane = threadIdx.x & 63;
  const int w = threadIdx.x >> 6;
  const int g = lane >> 4, c = lane & 15;
  const int wm = (w >> 1) * 64, wn = (w & 1) * 64;
#pragma unroll
  for (int mi = 0; mi < 4; ++mi)
#pragma unroll
    for (int ni = 0; ni < 4; ++ni)
#pragma unroll
      for (int r = 0; r < 4; ++r) {
        const int row = bm + wm + mi * 16 + g * 4 + r;
        const int col = bn + wn + ni * 16 + c;
        Y[(size_t)row * DM + col] = acc[mi][ni][r];
      }
}

// ---------------- Causal flash attention (T12 in-register P exchange) -------
// R19 structure, but P goes to the PV fragments via a 2-round cross-lane
// butterfly instead of the Pl LDS round-trip. Source: lane(g,c) holds
// P[q=c][kv=m*16+g*4+r]; target: pfa[j]=P[c][g*8+j], pfb[j]=P[c][32+g*8+j].
// Round1 shfl_xor48 (send parity !(g>>1)), Round2 shfl_xor16 (send k1 if
// (g&1)^(g>>1) else r1), final half-order select by g>>1. Verified lane-map.
__global__ __launch_bounds__(256) void attn_kernel(
    const __bf16* __restrict__ Qw, const __bf16* __restrict__ Kw,
    const __bf16* __restrict__ Vtw, __bf16* __restrict__ Ow) {
  __shared__ __bf16 Ks[2][64][72];
  __shared__ __bf16 Vt[2][64][72];
  const int tid = threadIdx.x;
  const int lane = tid & 63;
  const int wv = tid >> 6;
  const int g = lane >> 4, c = lane & 15;
  const int bid = blockIdx.x;          // 0..511
  const int half = bid >> 8;           // dispatch half
  const int idx = bid & 255;
  const int bh = idx & 31;
  const int gg = idx >> 5;             // 0..7
  const int gq = half ? (15 - gg) : gg;  // granule pair id 0..15
  const int diag0 = gq, diag1 = 31 - gq;
  const int NTb = 32 - gq;             // tile iterations (t = 0..31-gq)
  const size_t base = (size_t)bh * SEQ * DKK;
  const int qb[2] = {gq * 64 + wv * 16, (31 - gq) * 64 + wv * 16};
  bf16x8 qf[2][2];
#pragma unroll
  for (int f = 0; f < 2; ++f) {
    const __bf16* qp = Qw + base + (size_t)(qb[f] + c) * DKK + g * 8;
    qf[f][0] = *(const bf16x8*)qp;
    qf[f][1] = *(const bf16x8*)(qp + 32);
  }
  f32x4 oacc[2][4] = {};
  float m_r[2] = {-3e38f, -3e38f};
  float l_r[2] = {0.f, 0.f};
  const int srow = tid >> 3;               // 0..31
  const int sseg = (tid & 7) * 8;          // 0..56
  const __bf16* Kb = Kw + base;            // [kv][d]
  const __bf16* Vb = Vtw + base;           // [t][d][kv]
  const int ghi = g >> 1, gb = g & 1;
  bf16x8 kreg[2], vreg[2];
  // prologue: tile 0 -> LDS buf0; tile 1 -> regs; barrier
#pragma unroll
  for (int pass = 0; pass < 2; ++pass) {
    const int row = srow + pass * 32;
    *(bf16x8*)&Ks[0][row][sseg] = *(const bf16x8*)(Kb + (size_t)row * 64 + sseg);
    *(bf16x8*)&Vt[0][row][sseg] = *(const bf16x8*)(Vb + (size_t)row * 64 + sseg);
  }
#pragma unroll
  for (int pass = 0; pass < 2; ++pass) {
    const int row = srow + pass * 32;
    kreg[pass] = *(const bf16x8*)(Kb + (size_t)(64 + row) * 64 + sseg);
    vreg[pass] = *(const bf16x8*)(Vb + (size_t)(64 * 64) + row * 64 + sseg);
  }
  __syncthreads();
  for (int t = 0; t < NTb; ++t) {
    const int cur = t & 1;
    if (t + 1 < NTb) {
#pragma unroll
      for (int pass = 0; pass < 2; ++pass) {
        const int row = srow + pass * 32;
        *(bf16x8*)&Ks[cur ^ 1][row][sseg] = kreg[pass];
        *(bf16x8*)&Vt[cur ^ 1][row][sseg] = vreg[pass];
      }
      if (t + 2 < NTb) {
        const size_t ko = (size_t)(t + 2) * 64 * 64;
#pragma unroll
        for (int pass = 0; pass < 2; ++pass) {
          const int row = srow + pass * 32;
          kreg[pass] = *(const bf16x8*)(Kb + ko + (size_t)row * 64 + sseg);
          vreg[pass] = *(const bf16x8*)(Vb + ko + (size_t)row * 64 + sseg);
        }
      }
    }
    const bool act0 = (t <= diag0);      // frag0 still in causal range
    {
      bf16x8 kb0[4], kb1[4];
#pragma unroll
      for (int m = 0; m < 4; ++m) {
        kb0[m] = *(const bf16x8*)&Ks[cur][m * 16 + c][g * 8];
        kb1[m] = *(const bf16x8*)&Ks[cur][m * 16 + c][32 + g * 8];
      }
      f32x4 sac[2][4];
      __builtin_amdgcn_s_setprio(1);
#pragma unroll
      for (int m = 0; m < 4; ++m) {
        f32x4 zz = {};
        zz = MFMA16(kb0[m], qf[1][0], zz);
        sac[1][m] = MFMA16(kb1[m], qf[1][1], zz);
      }
      if (act0) {
#pragma unroll
        for (int m = 0; m < 4; ++m) {
          f32x4 zz = {};
          zz = MFMA16(kb0[m], qf[0][0], zz);
          sac[0][m] = MFMA16(kb1[m], qf[0][1], zz);
        }
      }
      __builtin_amdgcn_s_setprio(0);
      bf16x8 pA[2], pB[2];
#pragma unroll
      for (int f = 0; f < 2; ++f) {
        if (f == 0 && !act0) continue;
        const bool masked = (t == (f ? diag1 : diag0));
        const int qloc = qb[f] + c - t * 64;
        float sv[16];
        float mx = -3e38f;
#pragma unroll
        for (int m = 0; m < 4; ++m)
#pragma unroll
          for (int r = 0; r < 4; ++r) {
            float x = sac[f][m][r];   // Q pre-scaled: already in log2 units
            if (masked && (m * 16 + g * 4 + r > qloc)) x = -3e38f;
            sv[m * 4 + r] = x;
            mx = fmaxf(mx, x);
          }
        mx = fmaxf(mx, __shfl_xor(mx, 16, 64));
        mx = fmaxf(mx, __shfl_xor(mx, 32, 64));
        if (!__all(mx <= m_r[f] + 8.f)) {  // T13 defer-max
          const float mn = fmaxf(m_r[f], mx);
          const float al = exp2f(m_r[f] - mn);
          m_r[f] = mn;
          l_r[f] *= al;
#pragma unroll
          for (int ob = 0; ob < 4; ++ob)
#pragma unroll
            for (int r = 0; r < 4; ++r) oacc[f][ob][r] *= al;
        }
        float rs = 0.f;
        uint2 cl[4];
#pragma unroll
        for (int m = 0; m < 4; ++m) {
          bf16x4 pq;
#pragma unroll
          for (int r = 0; r < 4; ++r) {
            const float pexp = exp2f(sv[m * 4 + r] - m_r[f]);
            rs += pexp;
            pq[r] = (__bf16)pexp;
          }
          cl[m] = __builtin_bit_cast(uint2, pq);
        }
        rs += __shfl_xor(rs, 16, 64);
        rs += __shfl_xor(rs, 32, 64);
        l_r[f] += rs;
        // ---- T12 butterfly: cells -> PV B-fragments ----
        // R1 (xor48): send parity !(ghi)
        uint2 s1a = ghi ? cl[0] : cl[1];
        uint2 s1b = ghi ? cl[2] : cl[3];
        uint2 k1a = ghi ? cl[1] : cl[0];
        uint2 k1b = ghi ? cl[3] : cl[2];
        uint2 r1a, r1b;
        r1a.x = __shfl_xor(s1a.x, 48, 64);
        r1a.y = __shfl_xor(s1a.y, 48, 64);
        r1b.x = __shfl_xor(s1b.x, 48, 64);
        r1b.y = __shfl_xor(s1b.y, 48, 64);
        // R2 (xor16): lanes with gb^ghi send kept, else send received
        const int x2 = gb ^ ghi;
        uint2 s2a = x2 ? k1a : r1a;
        uint2 s2b = x2 ? k1b : r1b;
        uint2 t1a = x2 ? r1a : k1a;
        uint2 t1b = x2 ? r1b : k1b;
        uint2 q2a, q2b;
        q2a.x = __shfl_xor(s2a.x, 16, 64);
        q2a.y = __shfl_xor(s2a.y, 16, 64);
        q2b.x = __shfl_xor(s2b.x, 16, 64);
        q2b.y = __shfl_xor(s2b.y, 16, 64);
        // final half-order: lanes g>=2 have (s1,s0) -> swap
        uint2 A0 = ghi ? q2a : t1a;
        uint2 B0 = ghi ? t1a : q2a;
        uint2 A1 = ghi ? q2b : t1b;
        uint2 B1 = ghi ? t1b : q2b;
        union { uint32_t u[4]; bf16x8 v; } Pa, Pb;
        Pa.u[0] = A0.x; Pa.u[1] = A0.y; Pa.u[2] = B0.x; Pa.u[3] = B0.y;
        Pb.u[0] = A1.x; Pb.u[1] = A1.y; Pb.u[2] = B1.x; Pb.u[3] = B1.y;
        pA[f] = Pa.v;
        pB[f] = Pb.v;
      }
      __builtin_amdgcn_s_setprio(1);
#pragma unroll
      for (int ob = 0; ob < 4; ++ob) {     // V fragments shared by both frags
        const int d = ob * 16 + c;
        const bf16x8 vb0 = *(const bf16x8*)&Vt[cur][d][g * 8];
        const bf16x8 vb1 = *(const bf16x8*)&Vt[cur][d][32 + g * 8];
        oacc[1][ob] = MFMA16(vb0, pA[1], oacc[1][ob]);
        oacc[1][ob] = MFMA16(vb1, pB[1], oacc[1][ob]);
        if (act0) {
          oacc[0][ob] = MFMA16(vb0, pA[0], oacc[0][ob]);
          oacc[0][ob] = MFMA16(vb1, pB[0], oacc[0][ob]);
        }
      }
      __builtin_amdgcn_s_setprio(0);
    }
    __syncthreads();  // single barrier per tile
  }
  const int b = bh >> 4, h = bh & 15;
#pragma unroll
  for (int f = 0; f < 2; ++f) {
    const int q = qb[f] + c;
    const float inv = 1.0f / l_r[f];
#pragma unroll
    for (int ob = 0; ob < 4; ++ob) {
      bf16x4 st;
#pragma unroll
      for (int r = 0; r < 4; ++r) st[r] = (__bf16)(oacc[f][ob][r] * inv);
      *(bf16x4*)&Ow[(size_t)(b * SEQ + q) * DM + h * 64 + ob * 16 + g * 4] = st;
    }
  }
}

extern "C" void kernel_launch(void* const* d_in, const int* in_sizes, int n_in,
                              void* d_out, int out_size, void* d_ws,
                              size_t ws_size, hipStream_t stream) {
  const float* q = (const float*)d_in[0];
  const float* k = (const float*)d_in[1];
  const float* v = (const float*)d_in[2];
  // d_in[3] = mask (tril) — causality is hard-coded in attn_kernel
  const float* Wq = (const float*)d_in[4];
  const float* Wk = (const float*)d_in[5];
  const float* Wv = (const float*)d_in[6];
  const float* Wo = (const float*)d_in[7];
  __bf16* ws = (__bf16*)d_ws;
  const size_t SZ = (size_t)NB * NH * SEQ * DKK;  // 4,194,304 elems
  const size_t WZ = (size_t)DM * DM;              // 1,048,576 elems
  __bf16* qws = ws;
  __bf16* kws = ws + SZ;
  __bf16* vws = ws + 2 * SZ;   // transposed-tile layout
  __bf16* wqb = ws + 3 * SZ;
  __bf16* wkb = wqb + WZ;
  __bf16* wvb = wkb + WZ;
  __bf16* wob = wvb + WZ;
  __bf16* ows = wob + WZ;      // attn output (B,S,DM) bf16
  cvt_w_kernel<<<dim3(2048), 256, 0, stream>>>(
      Wq, Wk, Wv, Wo, wqb, wkb, wvb, wob);
  proj3_kernel<<<dim3(768), 256, 0, stream>>>(
      q, k, v, wqb, wkb, wvb, qws, kws, vws);
  attn_kernel<<<dim3(512), 256, 0, stream>>>(qws, kws, vws, ows);
  out_gemm_kernel<<<dim3(256), 256, 0, stream>>>(
      ows, wob, (float*)d_out);
}

// Round 21
// 131.289 us; speedup vs baseline: 1.0198x; 1.0198x over previous
//
#include <hip/hip_runtime.h>
#include <hip/hip_bf16.h>

typedef __attribute__((ext_vector_type(8))) __bf16 bf16x8;
typedef __attribute__((ext_vector_type(4))) __bf16 bf16x4;
typedef __attribute__((ext_vector_type(4))) float f32x4;

#define MFMA16(a, b, c) __builtin_amdgcn_mfma_f32_16x16x32_bf16((a), (b), (c), 0, 0, 0)

static constexpr int DM = 1024;
static constexpr int SEQ = 2048;
static constexpr int NB = 2;
static constexpr int NH = 16;
static constexpr int DKK = 64;
static constexpr int MROWS = NB * SEQ;  // 4096

__device__ __forceinline__ void gload16(__bf16* lds, const __bf16* g) {
  __builtin_amdgcn_global_load_lds(
      (const __attribute__((address_space(1))) void*)g,
      (__attribute__((address_space(3))) void*)lds, 16, 0, 0);
}

// ---------------- fp32 -> bf16 weight pre-convert (4 weights only) ----------
__global__ __launch_bounds__(256) void cvt_w_kernel(
    const float* __restrict__ wq, const float* __restrict__ wk,
    const float* __restrict__ wv, const float* __restrict__ wo,
    __bf16* __restrict__ owq, __bf16* __restrict__ owk,
    __bf16* __restrict__ owv, __bf16* __restrict__ owo) {
  const unsigned id = blockIdx.x * 256 + threadIdx.x;  // 524,288 threads
  const int sel = id >> 17;
  const float* src = sel == 0 ? wq : sel == 1 ? wk : sel == 2 ? wv : wo;
  __bf16* dst = sel == 0 ? owq : sel == 1 ? owk : sel == 2 ? owv : owo;
  const size_t off = (size_t)(id & ((1u << 17) - 1)) * 8;
  f32x4 a = *(const f32x4*)(src + off);
  f32x4 b2 = *(const f32x4*)(src + off + 4);
  bf16x8 o;
#pragma unroll
  for (int j = 0; j < 4; ++j) { o[j] = (__bf16)a[j]; o[j + 4] = (__bf16)b2[j]; }
  *(bf16x8*)(dst + off) = o;
}

// ---------------- all-bf16 GEMM core (global_load_lds, dbuf, 1 barrier/K) ---
__device__ __forceinline__ void gemm_bt_core(
    const __bf16* __restrict__ X, const __bf16* __restrict__ W, int bm, int bn,
    f32x4 (&acc)[4][4], __bf16 (*As)[128][32], __bf16 (*Bs)[128][32]) {
  const int tid = threadIdx.x;
  const int lane = tid & 63;
  const int w = tid >> 6;
  const int g = lane >> 4, c = lane & 15;
  const int wm = (w >> 1) * 64, wn = (w & 1) * 64;
  const int lrow = lane >> 2;          // 0..15
  const int lseg = (lane & 3) * 8;     // 0,8,16,24
  auto stage = [&](int b, int k0) {
#pragma unroll
    for (int j = 0; j < 2; ++j) {
      const int r0 = w * 32 + j * 16;  // wave-uniform LDS base; HW adds lane*16
      gload16(&As[b][r0][0], X + (size_t)(bm + r0 + lrow) * DM + k0 + lseg);
      gload16(&Bs[b][r0][0], W + (size_t)(bn + r0 + lrow) * DM + k0 + lseg);
    }
  };
  stage(0, 0);
  __syncthreads();  // vmcnt(0) drain + barrier: tile 0 ready
  for (int ks = 0; ks < DM / 32; ++ks) {
    if (ks + 1 < DM / 32) stage((ks + 1) & 1, (ks + 1) * 32);  // in flight
    const int b = ks & 1;
    bf16x8 af[4], bfr[4];
#pragma unroll
    for (int i = 0; i < 4; ++i) {
      af[i] = *(const bf16x8*)&As[b][wm + i * 16 + c][g * 8];
      bfr[i] = *(const bf16x8*)&Bs[b][wn + i * 16 + c][g * 8];
    }
#pragma unroll
    for (int mi = 0; mi < 4; ++mi)
#pragma unroll
      for (int ni = 0; ni < 4; ++ni)
        acc[mi][ni] = MFMA16(af[mi], bfr[ni], acc[mi][ni]);
    __syncthreads();  // drains next tile's loads; one barrier per K-step
  }
}

// ---------------- Fused Q/K/V projection (fp32 X, 2-deep A prefetch) --------
// XCD-chunked swizzle (T1) keeps each fp32 A-panel in ONE XCD L2.
// A-staging 2-deep (raA/raB, unroll-2 static names): ldA(k+2) issues at
// step k's top, consumed by stA at step k+1's bottom -> ~1.5 K-steps of
// latency cover. B via global_load_lds. Q/K: Y[b,h,s,dk] (Q pre-scaled by
// 0.125*log2e); V: transposed tiles [bh][s>>6][dk][s&63].
__global__ __launch_bounds__(256, 2) void proj3_kernel(
    const float* __restrict__ Xq, const float* __restrict__ Xk,
    const float* __restrict__ Xv, const __bf16* __restrict__ Wq,
    const __bf16* __restrict__ Wk, const __bf16* __restrict__ Wv,
    __bf16* __restrict__ Yq, __bf16* __restrict__ Yk, __bf16* __restrict__ Yv) {
  __shared__ __bf16 As[2][128][32];
  __shared__ __bf16 Bs[2][128][32];
  const int bid = blockIdx.x;          // 0..767
  const int swz = (bid & 7) * 96 + (bid >> 3);  // bijective: 768 = 8*96
  const int z = swz >> 8;              // 0..2
  const int rem = swz & 255;
  const int bm = (rem >> 3) * 128;
  const int bn = (rem & 7) * 128;
  const float* X = (z == 0) ? Xq : (z == 1) ? Xk : Xv;
  const __bf16* W = (z == 0) ? Wq : (z == 1) ? Wk : Wv;
  __bf16* Y = (z == 0) ? Yq : (z == 1) ? Yk : Yv;
  const int tid = threadIdx.x;
  const int lane = tid & 63;
  const int w = tid >> 6;
  const int g = lane >> 4, c = lane & 15;
  const int wm = (w >> 1) * 64, wn = (w & 1) * 64;
  const int srow = tid >> 1;           // 0..127 (A-staging row)
  const int shalf = (tid & 1) * 16;    // 0 or 16
  const int lrow = lane >> 2;          // 0..15  (B-staging)
  const int lseg = (lane & 3) * 8;
  const float* ap0 = X + (size_t)(bm + srow) * DM + shalf;
  f32x4 raA[4], raB[4];
  auto ldTo = [&](f32x4 (&ra)[4], int k0) {
#pragma unroll
    for (int i = 0; i < 4; ++i) ra[i] = *(const f32x4*)(ap0 + k0 + i * 4);
  };
  auto stFrom = [&](int b, const f32x4 (&ra)[4]) {
    bf16x8 h0, h1;
#pragma unroll
    for (int j = 0; j < 8; ++j) {
      h0[j] = (__bf16)ra[j >> 2][j & 3];
      h1[j] = (__bf16)ra[2 + (j >> 2)][j & 3];
    }
    *(bf16x8*)&As[b][srow][shalf] = h0;
    *(bf16x8*)&As[b][srow][shalf + 8] = h1;
  };
  auto stB = [&](int b, int k0) {
#pragma unroll
    for (int j = 0; j < 2; ++j) {
      const int r0 = w * 32 + j * 16;  // wave-uniform base; HW adds lane*16
      gload16(&Bs[b][r0][0], W + (size_t)(bn + r0 + lrow) * DM + k0 + lseg);
    }
  };
  f32x4 acc[4][4] = {};
  // prologue: tile0 -> LDS buf0 (via raB scratch); tile1 -> raA; B tile0
  ldTo(raB, 0);
  stB(0, 0);
  stFrom(0, raB);
  ldTo(raA, 32);
  __syncthreads();  // drains gload (vmcnt) + ds_write (lgkm): tile 0 ready
  // 32 K-steps, unrolled by 2 so ra names stay static (rule #20)
  for (int kk = 0; kk < 16; ++kk) {
    {  // even step: ks = 2kk, LDS buf0; raA holds tile ks+1
      const int ks = kk * 2;
      if (ks + 2 < 32) ldTo(raB, (ks + 2) * 32);
      if (ks + 1 < 32) stB(1, (ks + 1) * 32);
      bf16x8 af[4], bfr[4];
#pragma unroll
      for (int i = 0; i < 4; ++i) {
        af[i] = *(const bf16x8*)&As[0][wm + i * 16 + c][g * 8];
        bfr[i] = *(const bf16x8*)&Bs[0][wn + i * 16 + c][g * 8];
      }
#pragma unroll
      for (int mi = 0; mi < 4; ++mi)
#pragma unroll
        for (int ni = 0; ni < 4; ++ni)
          acc[mi][ni] = MFMA16(af[mi], bfr[ni], acc[mi][ni]);
      if (ks + 1 < 32) stFrom(1, raA);
      __syncthreads();
    }
    {  // odd step: ks = 2kk+1, LDS buf1; raB holds tile ks+1
      const int ks = kk * 2 + 1;
      if (ks + 2 < 32) ldTo(raA, (ks + 2) * 32);
      if (ks + 1 < 32) stB(0, (ks + 1) * 32);
      bf16x8 af[4], bfr[4];
#pragma unroll
      for (int i = 0; i < 4; ++i) {
        af[i] = *(const bf16x8*)&As[1][wm + i * 16 + c][g * 8];
        bfr[i] = *(const bf16x8*)&Bs[1][wn + i * 16 + c][g * 8];
      }
#pragma unroll
      for (int mi = 0; mi < 4; ++mi)
#pragma unroll
        for (int ni = 0; ni < 4; ++ni)
          acc[mi][ni] = MFMA16(af[mi], bfr[ni], acc[mi][ni]);
      if (ks + 1 < 32) stFrom(0, raB);
      __syncthreads();
    }
  }
  if (z == 2) {
    // V: transposed-tile layout [bh][s>>6][dk][s&63]; r-contiguous b64 stores
#pragma unroll
    for (int mi = 0; mi < 4; ++mi)
#pragma unroll
      for (int ni = 0; ni < 4; ++ni) {
        const int row = bm + wm + mi * 16 + g * 4;  // +r
        const int col = bn + wn + ni * 16 + c;
        const int b = row >> 11;
        const int s = row & (SEQ - 1);
        const int h = col >> 6;
        const int dk = col & 63;
        bf16x4 st;
#pragma unroll
        for (int r = 0; r < 4; ++r) st[r] = (__bf16)acc[mi][ni][r];
        *(bf16x4*)&Y[((size_t)((b * NH + h) * 32 + (s >> 6)) << 12) +
                     dk * 64 + (s & 63)] = st;
      }
  } else {
    // Q gets softmax scale folded in: 1/sqrt(64) * log2(e)
    const float qs = (z == 0) ? 0.1803368801f : 1.0f;
#pragma unroll
    for (int mi = 0; mi < 4; ++mi)
#pragma unroll
      for (int ni = 0; ni < 4; ++ni)
#pragma unroll
        for (int r = 0; r < 4; ++r) {
          const int row = bm + wm + mi * 16 + g * 4 + r;
          const int col = bn + wn + ni * 16 + c;
          const int b = row >> 11;
          const int s = row & (SEQ - 1);
          const int h = col >> 6;
          const int dk = col & 63;
          Y[((size_t)((b * NH + h) * SEQ + s) << 6) + dk] =
              (__bf16)(acc[mi][ni][r] * qs);
        }
  }
}

// ---------------- Output GEMM (XCD-chunked swizzle) ----------------
__global__ __launch_bounds__(256) void out_gemm_kernel(
    const __bf16* __restrict__ X, const __bf16* __restrict__ W,
    float* __restrict__ Y) {
  __shared__ __bf16 As[2][128][32];
  __shared__ __bf16 Bs[2][128][32];
  const int bid = blockIdx.x;          // 0..255
  const int swz = (bid & 7) * 32 + (bid >> 3);  // bijective: 256 = 8*32
  const int bm = (swz >> 3) * 128;
  const int bn = (swz & 7) * 128;
  f32x4 acc[4][4] = {};
  gemm_bt_core(X, W, bm, bn, acc, As, Bs);
  const int lane = threadIdx.x & 63;
  const int w = threadIdx.x >> 6;
  const int g = lane >> 4, c = lane & 15;
  const int wm = (w >> 1) * 64, wn = (w & 1) * 64;
#pragma unroll
  for (int mi = 0; mi < 4; ++mi)
#pragma unroll
    for (int ni = 0; ni < 4; ++ni)
#pragma unroll
      for (int r = 0; r < 4; ++r) {
        const int row = bm + wm + mi * 16 + g * 4 + r;
        const int col = bn + wn + ni * 16 + c;
        Y[(size_t)row * DM + col] = acc[mi][ni][r];
      }
}

// ---------------- Causal flash attention (best-known structure) -------------
// Q,K: (B,H,S,64) bf16 (Q pre-scaled).  V: transposed tiles [bh][32][64][64].
// Each block owns TWO complementary 64-row q-granules: gq (frag0, active for
// kv-tiles t<=gq) and 31-gq (frag1, active for all t). Block runs 32-gq tile
// iterations = 33 frag-visits for every gq; dispatch halves pair gq with
// 15-gq per CU so all CUs carry ~49 iterations. K/V double-buffered LDS,
// 1 barrier/tile, reg prefetch; swapped QK^T; T5 setprio; T13 defer-max.
__global__ __launch_bounds__(256) void attn_kernel(
    const __bf16* __restrict__ Qw, const __bf16* __restrict__ Kw,
    const __bf16* __restrict__ Vtw, __bf16* __restrict__ Ow) {
  __shared__ __bf16 Ks[2][64][72];
  __shared__ __bf16 Vt[2][64][72];
  __shared__ __bf16 Pl[4][32][72];
  const int tid = threadIdx.x;
  const int lane = tid & 63;
  const int wv = tid >> 6;
  const int g = lane >> 4, c = lane & 15;
  const int bid = blockIdx.x;          // 0..511
  const int half = bid >> 8;           // dispatch half
  const int idx = bid & 255;
  const int bh = idx & 31;
  const int gg = idx >> 5;             // 0..7
  const int gq = half ? (15 - gg) : gg;  // granule pair id 0..15
  const int diag0 = gq, diag1 = 31 - gq;
  const int NTb = 32 - gq;             // tile iterations (t = 0..31-gq)
  const size_t base = (size_t)bh * SEQ * DKK;
  const int qb[2] = {gq * 64 + wv * 16, (31 - gq) * 64 + wv * 16};
  bf16x8 qf[2][2];
#pragma unroll
  for (int f = 0; f < 2; ++f) {
    const __bf16* qp = Qw + base + (size_t)(qb[f] + c) * DKK + g * 8;
    qf[f][0] = *(const bf16x8*)qp;
    qf[f][1] = *(const bf16x8*)(qp + 32);
  }
  f32x4 oacc[2][4] = {};
  float m_r[2] = {-3e38f, -3e38f};
  float l_r[2] = {0.f, 0.f};
  const int srow = tid >> 3;               // 0..31
  const int sseg = (tid & 7) * 8;          // 0..56
  const __bf16* Kb = Kw + base;            // [kv][d]
  const __bf16* Vb = Vtw + base;           // [t][d][kv]
  bf16x8 kreg[2], vreg[2];
  // prologue: tile 0 -> LDS buf0; tile 1 -> regs; barrier
#pragma unroll
  for (int pass = 0; pass < 2; ++pass) {
    const int row = srow + pass * 32;
    *(bf16x8*)&Ks[0][row][sseg] = *(const bf16x8*)(Kb + (size_t)row * 64 + sseg);
    *(bf16x8*)&Vt[0][row][sseg] = *(const bf16x8*)(Vb + (size_t)row * 64 + sseg);
  }
#pragma unroll
  for (int pass = 0; pass < 2; ++pass) {
    const int row = srow + pass * 32;
    kreg[pass] = *(const bf16x8*)(Kb + (size_t)(64 + row) * 64 + sseg);
    vreg[pass] = *(const bf16x8*)(Vb + (size_t)(64 * 64) + row * 64 + sseg);
  }
  __syncthreads();
  for (int t = 0; t < NTb; ++t) {
    const int cur = t & 1;
    if (t + 1 < NTb) {
      // write tile t+1 into the other buffer (consumes prefetch regs)
#pragma unroll
      for (int pass = 0; pass < 2; ++pass) {
        const int row = srow + pass * 32;
        *(bf16x8*)&Ks[cur ^ 1][row][sseg] = kreg[pass];
        *(bf16x8*)&Vt[cur ^ 1][row][sseg] = vreg[pass];
      }
      if (t + 2 < NTb) {  // issue prefetch t+2; latency hides under compute
        const size_t ko = (size_t)(t + 2) * 64 * 64;
#pragma unroll
        for (int pass = 0; pass < 2; ++pass) {
          const int row = srow + pass * 32;
          kreg[pass] = *(const bf16x8*)(Kb + ko + (size_t)row * 64 + sseg);
          vreg[pass] = *(const bf16x8*)(Vb + ko + (size_t)row * 64 + sseg);
        }
      }
    }
    const bool act0 = (t <= diag0);      // frag0 still in causal range
    {
      bf16x8 kb0[4], kb1[4];
#pragma unroll
      for (int m = 0; m < 4; ++m) {
        kb0[m] = *(const bf16x8*)&Ks[cur][m * 16 + c][g * 8];
        kb1[m] = *(const bf16x8*)&Ks[cur][m * 16 + c][32 + g * 8];
      }
      f32x4 sac[2][4];
      __builtin_amdgcn_s_setprio(1);
#pragma unroll
      for (int m = 0; m < 4; ++m) {
        f32x4 zz = {};
        zz = MFMA16(kb0[m], qf[1][0], zz);
        sac[1][m] = MFMA16(kb1[m], qf[1][1], zz);
      }
      if (act0) {
#pragma unroll
        for (int m = 0; m < 4; ++m) {
          f32x4 zz = {};
          zz = MFMA16(kb0[m], qf[0][0], zz);
          sac[0][m] = MFMA16(kb1[m], qf[0][1], zz);
        }
      }
      __builtin_amdgcn_s_setprio(0);
#pragma unroll
      for (int f = 0; f < 2; ++f) {
        if (f == 0 && !act0) continue;
        const bool masked = (t == (f ? diag1 : diag0));
        const int qloc = qb[f] + c - t * 64;
        float sv[16];
        float mx = -3e38f;
#pragma unroll
        for (int m = 0; m < 4; ++m)
#pragma unroll
          for (int r = 0; r < 4; ++r) {
            float x = sac[f][m][r];   // Q pre-scaled: already in log2 units
            if (masked && (m * 16 + g * 4 + r > qloc)) x = -3e38f;
            sv[m * 4 + r] = x;
            mx = fmaxf(mx, x);
          }
        mx = fmaxf(mx, __shfl_xor(mx, 16, 64));
        mx = fmaxf(mx, __shfl_xor(mx, 32, 64));
        if (!__all(mx <= m_r[f] + 8.f)) {  // T13 defer-max
          const float mn = fmaxf(m_r[f], mx);
          const float al = exp2f(m_r[f] - mn);
          m_r[f] = mn;
          l_r[f] *= al;
#pragma unroll
          for (int ob = 0; ob < 4; ++ob)
#pragma unroll
            for (int r = 0; r < 4; ++r) oacc[f][ob][r] *= al;
        }
        float rs = 0.f;
#pragma unroll
        for (int m = 0; m < 4; ++m) {
          bf16x4 pq;
#pragma unroll
          for (int r = 0; r < 4; ++r) {
            const float pexp = exp2f(sv[m * 4 + r] - m_r[f]);
            rs += pexp;
            pq[r] = (__bf16)pexp;
          }
          *(bf16x4*)&Pl[wv][f * 16 + c][m * 16 + g * 4] = pq;
        }
        rs += __shfl_xor(rs, 16, 64);
        rs += __shfl_xor(rs, 32, 64);
        l_r[f] += rs;
      }
      bf16x8 pf1a = *(const bf16x8*)&Pl[wv][16 + c][g * 8];
      bf16x8 pf1b = *(const bf16x8*)&Pl[wv][16 + c][32 + g * 8];
      bf16x8 pf0a, pf0b;
      if (act0) {
        pf0a = *(const bf16x8*)&Pl[wv][c][g * 8];
        pf0b = *(const bf16x8*)&Pl[wv][c][32 + g * 8];
      }
      __builtin_amdgcn_s_setprio(1);
#pragma unroll
      for (int ob = 0; ob < 4; ++ob) {     // V fragments shared by both frags
        const int d = ob * 16 + c;
        const bf16x8 vb0 = *(const bf16x8*)&Vt[cur][d][g * 8];
        const bf16x8 vb1 = *(const bf16x8*)&Vt[cur][d][32 + g * 8];
        oacc[1][ob] = MFMA16(vb0, pf1a, oacc[1][ob]);
        oacc[1][ob] = MFMA16(vb1, pf1b, oacc[1][ob]);
        if (act0) {
          oacc[0][ob] = MFMA16(vb0, pf0a, oacc[0][ob]);
          oacc[0][ob] = MFMA16(vb1, pf0b, oacc[0][ob]);
        }
      }
      __builtin_amdgcn_s_setprio(0);
    }
    __syncthreads();  // single barrier per tile
  }
  const int b = bh >> 4, h = bh & 15;
#pragma unroll
  for (int f = 0; f < 2; ++f) {
    const int q = qb[f] + c;
    const float inv = 1.0f / l_r[f];
#pragma unroll
    for (int ob = 0; ob < 4; ++ob) {
      bf16x4 st;
#pragma unroll
      for (int r = 0; r < 4; ++r) st[r] = (__bf16)(oacc[f][ob][r] * inv);
      *(bf16x4*)&Ow[(size_t)(b * SEQ + q) * DM + h * 64 + ob * 16 + g * 4] = st;
    }
  }
}

extern "C" void kernel_launch(void* const* d_in, const int* in_sizes, int n_in,
                              void* d_out, int out_size, void* d_ws,
                              size_t ws_size, hipStream_t stream) {
  const float* q = (const float*)d_in[0];
  const float* k = (const float*)d_in[1];
  const float* v = (const float*)d_in[2];
  // d_in[3] = mask (tril) — causality is hard-coded in attn_kernel
  const float* Wq = (const float*)d_in[4];
  const float* Wk = (const float*)d_in[5];
  const float* Wv = (const float*)d_in[6];
  const float* Wo = (const float*)d_in[7];
  __bf16* ws = (__bf16*)d_ws;
  const size_t SZ = (size_t)NB * NH * SEQ * DKK;  // 4,194,304 elems
  const size_t WZ = (size_t)DM * DM;              // 1,048,576 elems
  __bf16* qws = ws;
  __bf16* kws = ws + SZ;
  __bf16* vws = ws + 2 * SZ;   // transposed-tile layout
  __bf16* wqb = ws + 3 * SZ;
  __bf16* wkb = wqb + WZ;
  __bf16* wvb = wkb + WZ;
  __bf16* wob = wvb + WZ;
  __bf16* ows = wob + WZ;      // attn output (B,S,DM) bf16
  cvt_w_kernel<<<dim3(2048), 256, 0, stream>>>(
      Wq, Wk, Wv, Wo, wqb, wkb, wvb, wob);
  proj3_kernel<<<dim3(768), 256, 0, stream>>>(
      q, k, v, wqb, wkb, wvb, qws, kws, vws);
  attn_kernel<<<dim3(512), 256, 0, stream>>>(qws, kws, vws, ows);
  out_gemm_kernel<<<dim3(256), 256, 0, stream>>>(
      ows, wob, (float*)d_out);
}